// Round 18
// baseline (3597.944 us; speedup 1.0000x reference)
//
#include <hip/hip_runtime.h>
#include <cstdint>
#include <cstddef>

typedef __attribute__((ext_vector_type(8))) short short8;
typedef __attribute__((ext_vector_type(4))) short short4v;
typedef __attribute__((ext_vector_type(4))) float f32x4;
typedef __attribute__((ext_vector_type(4))) int int4v;
typedef __attribute__((ext_vector_type(2))) int int2v;

static constexpr int B_ = 64, T_ = 256, D_ = 1024, NH = 1024, NG = 4096;
// gemm LDS: union( As 16K + Bs 16K , Cs[128][264] 67.6K )
static constexpr int GEMM_LDS = 128 * 264 * 2;
// recurrence LDS: Us(i8) 128K | zsm [8][132] f32 4352B | scl 512B | pmax 2K
static constexpr int REC_LDS = 131072 + 4352 + 512 + 2048;

__device__ __forceinline__ short f2bs(float f) {
  union { float f; uint32_t u; } cv; cv.f = f;
  uint32_t u = cv.u;
  uint32_t r = (u + 0x7fffu + ((u >> 16) & 1u)) >> 16;  // RNE
  return (short)(uint16_t)r;
}
__device__ __forceinline__ float bs2f(short s) {
  union { uint32_t u; float f; } cv; cv.u = ((uint32_t)(uint16_t)s) << 16; return cv.f;
}
__device__ __forceinline__ float fsigm(float x) {
  return __builtin_amdgcn_rcpf(1.f + __expf(-x));
}
__device__ __forceinline__ float ftanh(float x) {
  return 1.f - 2.f * __builtin_amdgcn_rcpf(__expf(2.f * x) + 1.f);
}

// ---------------------------------------------------------------------------
// xz = x @ W + bias  (M=16384,K=1024,N=4096), bf16. r13's 256x256-tile GEMM;
// epilogue re-addressed to per-recurrence-block layout:
//   xzT[bid_rec][t][b_loc][gate][32uu], bid_rec = (u>>5)*8 + (b_glob>>3)
// ---------------------------------------------------------------------------
__global__ __launch_bounds__(512, 1) void xz_gemm(const float* __restrict__ x,
                                                  const float* __restrict__ W,
                                                  const float* __restrict__ bias,
                                                  short* __restrict__ xzT)
{
  constexpr int BM = 256, BN = 256, BK = 32;
  extern __shared__ char gsm[];
  short* As = (short*)gsm;              // [256][32]
  short* Bs = (short*)(gsm + 16384);    // [32][256]
  short* Cs = (short*)gsm;              // [128][264]  (reused after k-loop)

  const int tid  = threadIdx.x;
  const int lane = tid & 63, wave = tid >> 6;
  const int wm = (wave >> 2) * 128, wn = (wave & 3) * 64;
  const int fr = lane & 15, kg = lane >> 4;
  const int bm = blockIdx.x * BM, bn = blockIdx.y * BN;

  f32x4 acc[8][4] = {};

  for (int k0 = 0; k0 < D_; k0 += BK) {
    {  // stage A: 256 rows x 32 k
      const int r0 = tid >> 3, kq = (tid & 7) * 4;
      #pragma unroll
      for (int it = 0; it < 4; ++it) {
        const int row = r0 + it * 64;
        const float4 v = *reinterpret_cast<const float4*>(&x[(size_t)(bm + row) * D_ + k0 + kq]);
        short4v s; s.x = f2bs(v.x); s.y = f2bs(v.y); s.z = f2bs(v.z); s.w = f2bs(v.w);
        *reinterpret_cast<short4v*>(&As[row * 32 + kq]) = s;
      }
    }
    {  // stage B: 32 k-rows x 256 n
      const int kr0 = tid >> 6, nq = (tid & 63) * 4;
      #pragma unroll
      for (int it = 0; it < 4; ++it) {
        const int krow = kr0 + it * 8;
        const float4 v = *reinterpret_cast<const float4*>(&W[(size_t)(k0 + krow) * NG + bn + nq]);
        short4v s; s.x = f2bs(v.x); s.y = f2bs(v.y); s.z = f2bs(v.z); s.w = f2bs(v.w);
        *reinterpret_cast<short4v*>(&Bs[krow * 256 + nq]) = s;
      }
    }
    __syncthreads();

    short8 af[8];
    #pragma unroll
    for (int mi = 0; mi < 8; ++mi)
      af[mi] = *reinterpret_cast<const short8*>(&As[(wm + mi * 16 + fr) * 32 + kg * 8]);
    #pragma unroll
    for (int ni = 0; ni < 4; ++ni) {
      short8 bf;
      #pragma unroll
      for (int j = 0; j < 8; ++j) bf[j] = Bs[(kg * 8 + j) * 256 + wn + ni * 16 + fr];
      #pragma unroll
      for (int mi = 0; mi < 8; ++mi)
        acc[mi][ni] = __builtin_amdgcn_mfma_f32_16x16x32_bf16(af[mi], bf, acc[mi][ni], 0, 0, 0);
    }
    __syncthreads();
  }

  // Epilogue: two 128-row half passes through the LDS C-tile.
  const int fq = lane >> 4;
  const int bglob = blockIdx.x;        // bm tile == one batch
  const int gg    = bn >> 10;          // gate
  const int utile = bn & 1023;         // first unit of tile (mult of 256)
  #pragma unroll
  for (int hp = 0; hp < 2; ++hp) {
    __syncthreads();
    if ((wave >> 2) == hp) {
      #pragma unroll
      for (int ni = 0; ni < 4; ++ni) {
        const int col = wn + ni * 16 + fr;
        const float bv = bias[bn + col];
        #pragma unroll
        for (int mi = 0; mi < 8; ++mi) {
          const int rowl = mi * 16 + fq * 4;
          #pragma unroll
          for (int r = 0; r < 4; ++r)
            Cs[(rowl + r) * 264 + col] = f2bs(acc[mi][ni][r] + bv);
        }
      }
    }
    __syncthreads();
    // scatter: per (t, 16-unit chunk) one 32B run into the block-local layout
    #pragma unroll
    for (int it = 0; it < 4; ++it) {
      const int cid = it * 512 + tid;            // 0..2047
      const int tl = cid >> 4, rbi = cid & 15;
      const int t = hp * 128 + tl;
      const int ul = utile + rbi * 16;           // global unit base of chunk
      const int slc = ul >> 5, ub = ul & 31;     // ub in {0,16}
      const int bidr = slc * 8 + (bglob >> 3);
      short* dst = xzT + (size_t)bidr * 262144 + (size_t)t * 1024
                 + (bglob & 7) * 128 + gg * 32 + ub;
      const short8 v0 = *reinterpret_cast<const short8*>(&Cs[tl * 264 + rbi * 16]);
      const short8 v1 = *reinterpret_cast<const short8*>(&Cs[tl * 264 + rbi * 16 + 8]);
      *reinterpret_cast<short8*>(dst)     = v0;
      *reinterpret_cast<short8*>(dst + 8) = v1;
    }
  }
}

// ---------------------------------------------------------------------------
// Recurrence, batch-partitioned: 256 blocks x 512 thr, 1 block/CU.
// group g = bid&7 (batches 8g..8g+8) -- co-XCD by round-robin dispatch;
// slice sl = bid>>3 (units 32sl..32sl+32). Per step each of 8 waves does one
// 16-col n-tile x full K=1024 (32 i8 MFMAs); h_grp[8,1024] read as tagged
// (tag16|2xi8) u32 words from the LOCAL L2 (sc0), escalating to MALL
// (sc0 sc1) after 6 tries -- correct under any block placement. Producers
// double-store (sc0 + sc0sc1). M=16 pad rows 8-15 are constant zero.
// ---------------------------------------------------------------------------
#define WAITV(N) do { asm volatile("s_waitcnt vmcnt(" #N ")" ::: "memory"); \
                      __builtin_amdgcn_sched_barrier(0); } while (0)

#define H1F(B0, VO) \
  asm volatile("global_load_dwordx4 %0, %1, %2 sc0" \
               : "=&v"(B0) : "v"(VO), "s"(hpv) : "memory")
#define H1S(B0, VO) \
  asm volatile("global_load_dwordx4 %0, %1, %2 sc0 sc1" \
               : "=&v"(B0) : "v"(VO), "s"(hpv) : "memory")

#define ISSUE16F(BUF, BASE) { _Pragma("unroll") \
  for (int K = 0; K < 16; ++K) H1F(BUF[K], voff0 + (BASE) + K * 1024); }
#define ISSUE16S(BUF, BASE) { _Pragma("unroll") \
  for (int K = 0; K < 16; ++K) H1S(BUF[K], voff0 + (BASE) + K * 1024); }

#define CHECK16(BUF) { uint32_t bb = 0; _Pragma("unroll") \
  for (int i = 0; i < 16; ++i) { \
    bb |= ((uint32_t)BUF[i][0] ^ tgw); bb |= ((uint32_t)BUF[i][1] ^ tgw); \
    bb |= ((uint32_t)BUF[i][2] ^ tgw); bb |= ((uint32_t)BUF[i][3] ^ tgw); \
  } bad = frlt8 ? (bb & 0xFFFF0000u) : 0u; }

#define MFMA16(BUF, KB) { _Pragma("unroll") \
  for (int K = 0; K < 16; ++K) { \
    int2v ad; \
    ad[0] = (BUF[K][0] & 0xFFFF) | ((BUF[K][1] & 0xFFFF) << 16); \
    ad[1] = (BUF[K][2] & 0xFFFF) | ((BUF[K][3] & 0xFFFF) << 16); \
    const long long a64 = frlt8 ? __builtin_bit_cast(long long, ad) : 0ll; \
    const int ksAbs = (KB) + K; \
    const long long b64 = *reinterpret_cast<const long long*>( \
        &Us[(size_t)(((ksAbs * 4 + kg) * 128 + wave * 16 + fr)) * 8]); \
    acc = __builtin_amdgcn_mfma_i32_16x16x32_i8(a64, b64, acc, 0, 0, 0); \
  } }

__global__ __launch_bounds__(512, 2) void lstm_rec(
    const short* __restrict__ xzT, const float* __restrict__ U,
    uint32_t* __restrict__ h0buf, uint32_t* __restrict__ h1buf,
    float* __restrict__ out)
{
  extern __shared__ char smem[];
  char*  Us   = smem;                            // i8 [ks4kg][128c][8j] 128 KB
  float* zsm  = (float*)(smem + 131072);         // [8][132]
  float* scl  = (float*)(smem + 131072 + 4352);  // [128]
  float* pmax = (float*)(smem + 131072 + 4864);  // [4][128]

  const int tid  = threadIdx.x;
  const int lane = tid & 63, wave = tid >> 6;
  const int bid  = blockIdx.x;
  const int g    = bid & 7;        // batch group (XCD-affine by dispatch)
  const int sl   = bid >> 3;       // unit slice
  const int fr = lane & 15, kg = lane >> 4;
  const bool frlt8 = (fr < 8);

  // per-column |U| max (4-way parallel scan + reduce)
  {
    const int c = tid & 127, q = tid >> 7;
    const float* up = U + (size_t)(q * 256) * NG + (c >> 5) * NH + sl * 32 + (c & 31);
    float m = 1e-30f;
    for (int k = 0; k < 256; ++k) m = fmaxf(m, fabsf(up[(size_t)k * NG]));
    pmax[q * 128 + c] = m;
  }
  __syncthreads();
  if (tid < 128)
    scl[tid] = fmaxf(fmaxf(pmax[tid], pmax[128 + tid]),
                     fmaxf(pmax[256 + tid], pmax[384 + tid]));
  __syncthreads();
  // quantize U slice to i8, fragment-packed
  for (int idx = tid; idx < 131072; idx += 512) {
    const int k = idx >> 7, c = idx & 127;
    const float v = U[(size_t)k * NG + (c >> 5) * NH + sl * 32 + (c & 31)];
    Us[(size_t)(((k >> 5) * 4 + ((k >> 3) & 3)) * 128 + c) * 8 + (k & 7)] =
        (char)(int)rintf(v * (127.f / scl[c]));
  }
  const float sdiv = scl[wave * 16 + fr] * (1.f / 16129.f);
  float creg = 0.f;
  const int voff0 = kg * 256 + fr * 16;   // consumer byte offset base
  __syncthreads();

  for (int t = 0; t < T_; ++t) {
    const uint32_t* hpv = ((t & 1) ? h0buf : h1buf) + g * 8192;  // h(t-1)
    uint32_t*       hnx = ((t & 1) ? h1buf : h0buf) + g * 8192;  // h(t)

    // xz prefetch (plain loads, L3-resident; waits sink to gate phase)
    float xzv0 = 0.f, xzv1 = 0.f, xzv2 = 0.f, xzv3 = 0.f;
    if (tid < 256) {
      const short* xb = xzT + (size_t)bid * 262144 + (size_t)t * 1024
                      + (tid >> 5) * 128 + (tid & 31);
      xzv0 = bs2f(xb[0]);  xzv1 = bs2f(xb[32]);
      xzv2 = bs2f(xb[64]); xzv3 = bs2f(xb[96]);
    }

    int4v acc = {};
    if (t > 0) {
      const uint32_t tgw = (uint32_t)t << 16;
      int4v bufA[16], bufB[16];
      if (frlt8) { ISSUE16F(bufA, 0); ISSUE16F(bufB, 16384); }
      WAITV(16);
      {
        int tries = 0; uint32_t bad;
        for (;;) {
          CHECK16(bufA);
          if (__all(bad == 0)) break;
          __builtin_amdgcn_s_sleep(1);
          ++tries;
          if (frlt8) { if (tries < 6) { ISSUE16F(bufA, 0); } else { ISSUE16S(bufA, 0); } }
          WAITV(0);
        }
      }
      MFMA16(bufA, 0);
      WAITV(0);
      {
        int tries = 0; uint32_t bad;
        for (;;) {
          CHECK16(bufB);
          if (__all(bad == 0)) break;
          __builtin_amdgcn_s_sleep(1);
          ++tries;
          if (frlt8) { if (tries < 6) { ISSUE16F(bufB, 16384); } else { ISSUE16S(bufB, 16384); } }
          WAITV(0);
        }
      }
      MFMA16(bufB, 16);

      // C/D: col=lane&15, row=(lane>>4)*4+r ; rows 0-7 real
      if (lane < 32) {
        const int rowb = (lane >> 4) * 4;
        #pragma unroll
        for (int r = 0; r < 4; ++r)
          zsm[(rowb + r) * 132 + wave * 16 + fr] = (float)acc[r] * sdiv;
      }
    }
    __syncthreads();   // S1: z visible

    if (tid < 256) {   // gate math: b = tid>>5, unit uu = tid&31
      const int b = tid >> 5, uu = tid & 31;
      float z0 = xzv0, z1 = xzv1, z2 = xzv2, z3 = xzv3;
      if (t > 0) {
        z0 += zsm[b * 132 + uu];
        z1 += zsm[b * 132 + 32 + uu];
        z2 += zsm[b * 132 + 64 + uu];
        z3 += zsm[b * 132 + 96 + uu];
      }
      const float ig = fsigm(z0), fg = fsigm(z1);
      const float gg2 = ftanh(z2), og = fsigm(z3);
      creg = fg * creg + ig * gg2;
      const float hh = og * ftanh(creg);

      if (t < T_ - 1) {
        const int q = (int)rintf(hh * 127.f);
        const int qp = __shfl_xor(q, 1);
        if (!(uu & 1)) {
          const uint32_t word = ((uint32_t)(t + 1) << 16)
                              | (((uint32_t)qp & 0xFFu) << 8) | ((uint32_t)q & 0xFFu);
          uint32_t* hp = hnx + ((sl * 4 + (uu >> 3)) * 16 + b) * 4 + ((uu >> 1) & 3);
          // double store: local-L2 fast path + MALL write-through (idempotent)
          asm volatile("global_store_dword %0, %1, off sc0\n\t"
                       "global_store_dword %0, %1, off sc0 sc1"
                       :: "v"(hp), "v"(word) : "memory");
        }
      }
      out[((size_t)(8 * g + b) * 256 + t) * 1024 + 32 * sl + uu] = hh;
    }
    __builtin_amdgcn_s_barrier();   // zsm reuse fence (stores stay in flight)
  }
}

extern "C" void kernel_launch(void* const* d_in, const int* in_sizes, int n_in,
                              void* d_out, int out_size, void* d_ws, size_t ws_size,
                              hipStream_t stream) {
  const float* x    = (const float*)d_in[0];
  const float* W    = (const float*)d_in[1];
  const float* U    = (const float*)d_in[2];
  const float* bias = (const float*)d_in[3];
  float* out = (float*)d_out;
  char* ws = (char*)d_ws;

  // ws: xzT bf16 128 MiB | h ping/pong (tag|2xi8 words) 2 x 256 KiB
  short*    xzT = (short*)ws;
  uint32_t* hA  = (uint32_t*)(ws + 134217728);
  uint32_t* hB  = (uint32_t*)(ws + 134217728 + 262144);

  // zero h tags each launch (tag 0 never matches t>=1; graph replays rerun this)
  hipMemsetAsync(ws + 134217728, 0, 524288, stream);

  hipFuncSetAttribute((const void*)xz_gemm,
                      hipFuncAttributeMaxDynamicSharedMemorySize, GEMM_LDS);
  xz_gemm<<<dim3(64, 16), 512, GEMM_LDS, stream>>>(x, W, bias, xzT);

  hipFuncSetAttribute((const void*)lstm_rec,
                      hipFuncAttributeMaxDynamicSharedMemorySize, REC_LDS);
  lstm_rec<<<dim3(256), 512, REC_LDS, stream>>>(xzT, U, hA, hB, out);
}

// Round 19
// 1897.570 us; speedup vs baseline: 1.8961x; 1.8961x over previous
//
#include <hip/hip_runtime.h>
#include <cstdint>
#include <cstddef>

typedef __attribute__((ext_vector_type(8))) short short8;
typedef __attribute__((ext_vector_type(4))) short short4v;
typedef __attribute__((ext_vector_type(4))) float f32x4;
typedef __attribute__((ext_vector_type(4))) int int4v;

static constexpr int B_ = 64, T_ = 256, D_ = 1024, NH = 1024, NG = 4096;
static constexpr int NBLK = 64;          // recurrence blocks
static constexpr int NWRK = 96;          // gemm worker blocks
// LDS: recurrence Us 128K + zsm [64][68] f32 = 148480; gemm path uses < that
static constexpr int LDS_BYTES = 131072 + 64 * 68 * 4;
static constexpr uint64_t DLY_TICKS = 50;  // 0.5 us @ 100MHz s_memrealtime

__device__ __forceinline__ short f2bs(float f) {
  union { float f; uint32_t u; } cv; cv.f = f;
  uint32_t u = cv.u;
  uint32_t r = (u + 0x7fffu + ((u >> 16) & 1u)) >> 16;  // RNE
  return (short)(uint16_t)r;
}
__device__ __forceinline__ float bs2f(short s) {
  union { uint32_t u; float f; } cv; cv.u = ((uint32_t)(uint16_t)s) << 16; return cv.f;
}
__device__ __forceinline__ float fsigm(float x) {
  return __builtin_amdgcn_rcpf(1.f + __expf(-x));
}
__device__ __forceinline__ float ftanh(float x) {
  return 1.f - 2.f * __builtin_amdgcn_rcpf(__expf(2.f * x) + 1.f);
}
__device__ __forceinline__ uint64_t rtclock() {
  uint64_t v;
  asm volatile("s_memrealtime %0\n\ts_waitcnt lgkmcnt(0)" : "=s"(v));
  return v;
}

#define WAITV(N) do { asm volatile("s_waitcnt vmcnt(" #N ")" ::: "memory"); \
                      __builtin_amdgcn_sched_barrier(0); } while (0)

#define HL2(B0, B1, VO) \
  asm volatile("global_load_dwordx4 %0, %2, %3 sc0 sc1\n\t" \
               "global_load_dwordx4 %1, %2, %3 offset:16 sc0 sc1" \
               : "=&v"(B0), "=&v"(B1) : "v"(VO), "s"(hpv) : "memory")

#define ISSUE_A { _Pragma("unroll") \
  for (int K = 0; K < 8; ++K) HL2(bufA[2*K], bufA[2*K+1], voff0 + K * 8192); }
#define ISSUE_B { _Pragma("unroll") \
  for (int K = 0; K < 8; ++K) HL2(bufB[2*K], bufB[2*K+1], voff0 + 65536 + K * 8192); }

#define CHECKBUF(BUF) { _Pragma("unroll") \
  for (int i = 0; i < 16; ++i) { \
    bad |= ((uint32_t)BUF[i][0] ^ tgw); bad |= ((uint32_t)BUF[i][1] ^ tgw); \
    bad |= ((uint32_t)BUF[i][2] ^ tgw); bad |= ((uint32_t)BUF[i][3] ^ tgw); \
  } bad &= 0xFFFF0000u; }

#define MFMA_SUB(BUF, KB) { _Pragma("unroll") \
  for (int K = 0; K < 8; ++K) { \
    int4v pk; \
    pk[0] = (BUF[2*K][0]   & 0xFFFF) | (BUF[2*K][1]   << 16); \
    pk[1] = (BUF[2*K][2]   & 0xFFFF) | (BUF[2*K][3]   << 16); \
    pk[2] = (BUF[2*K+1][0] & 0xFFFF) | (BUF[2*K+1][1] << 16); \
    pk[3] = (BUF[2*K+1][2] & 0xFFFF) | (BUF[2*K+1][3] << 16); \
    const short8 fa = __builtin_bit_cast(short8, pk); \
    const int ksAbs = kh * 16 + (KB) + K; \
    _Pragma("unroll") \
    for (int nt = 0; nt < 4; ++nt) { \
      const short8 fb = *reinterpret_cast<const short8*>(&Us[((ksAbs*4 + kg)*64 + nt*16 + fr)*8]); \
      acc[nt] = __builtin_amdgcn_mfma_f32_16x16x32_bf16(fa, fb, acc[nt], 0, 0, 0); \
    } \
  } }

// ---------------------------------------------------------------------------
// FUSED kernel (round-16 champion, restored byte-for-byte):
// blocks [0,64) = persistent recurrence; blocks [64,160) = persistent GEMM
// workers producing xzT in t-order (ready[] gated). Recurrence: flag-free
// tagged h (tag16|bf16 u32), fragment-major coalesced sc0sc1 loads, 64-bit
// agent-scope atomic-exchange h stores, A/B counted-vmcnt pipeline, 0.5us
// pace, tag-check retry backstop.
// ---------------------------------------------------------------------------
__global__ __launch_bounds__(512, 1) void lstm_fused(
    const float* __restrict__ x, const float* __restrict__ W,
    const float* __restrict__ bias, const float* __restrict__ U,
    short* __restrict__ xzT, uint32_t* __restrict__ h0buf,
    uint32_t* __restrict__ h1buf, int* __restrict__ ready,
    float* __restrict__ out)
{
  extern __shared__ char smem[];
  const int tid  = threadIdx.x;
  const int lane = tid & 63, wave = tid >> 6;
  const int bid  = blockIdx.x;
  const int fr = lane & 15, kg = lane >> 4;

  if (bid >= NBLK) {
    // ================= GEMM worker =================
    short* As = (short*)smem;             // [256][32]
    short* Bs = (short*)(smem + 16384);   // [32][256]
    short* Cs = (short*)smem;             // [128][264] (reused after k-loop)
    const int wm = (wave >> 2) * 128, wn = (wave & 3) * 64;
    const int fq = lane >> 4;
    const int wid = bid - NBLK;

    for (int tile = wid; tile < 1024; tile += NWRK) {
      const int tt = tile >> 4;            // t in [4tt, 4tt+4)
      const int bn = (tile & 15) * 256;    // one gate, 16 rb
      f32x4 acc[8][4] = {};

      for (int k0 = 0; k0 < D_; k0 += 32) {
        {  // stage A: tile row r -> x row (m&63)*256 + (m>>6), m = tt*256+r
          const int r0 = tid >> 3, kq = (tid & 7) * 4;
          #pragma unroll
          for (int it = 0; it < 4; ++it) {
            const int r = r0 + it * 64;
            const int m = tt * 256 + r;
            const int xr = (m & 63) * 256 + (m >> 6);
            const float4 v = *reinterpret_cast<const float4*>(&x[(size_t)xr * D_ + k0 + kq]);
            short4v s; s.x = f2bs(v.x); s.y = f2bs(v.y); s.z = f2bs(v.z); s.w = f2bs(v.w);
            *reinterpret_cast<short4v*>(&As[r * 32 + kq]) = s;
          }
        }
        {  // stage B
          const int kr0 = tid >> 6, nq = (tid & 63) * 4;
          #pragma unroll
          for (int it = 0; it < 4; ++it) {
            const int krow = kr0 + it * 8;
            const float4 v = *reinterpret_cast<const float4*>(&W[(size_t)(k0 + krow) * NG + bn + nq]);
            short4v s; s.x = f2bs(v.x); s.y = f2bs(v.y); s.z = f2bs(v.z); s.w = f2bs(v.w);
            *reinterpret_cast<short4v*>(&Bs[krow * 256 + nq]) = s;
          }
        }
        __syncthreads();

        short8 af[8];
        #pragma unroll
        for (int mi = 0; mi < 8; ++mi)
          af[mi] = *reinterpret_cast<const short8*>(&As[(wm + mi * 16 + fr) * 32 + kg * 8]);
        #pragma unroll
        for (int ni = 0; ni < 4; ++ni) {
          short8 bf;
          #pragma unroll
          for (int j = 0; j < 8; ++j) bf[j] = Bs[(kg * 8 + j) * 256 + wn + ni * 16 + fr];
          #pragma unroll
          for (int mi = 0; mi < 8; ++mi)
            acc[mi][ni] = __builtin_amdgcn_mfma_f32_16x16x32_bf16(af[mi], bf, acc[mi][ni], 0, 0, 0);
        }
        __syncthreads();
      }

      // epilogue: two 128-row half passes through Cs; sc0sc1 scatter stores
      const int g = bn >> 10, rb0 = (bn & 1023) >> 4;
      #pragma unroll
      for (int hp = 0; hp < 2; ++hp) {
        __syncthreads();
        if ((wave >> 2) == hp) {
          #pragma unroll
          for (int ni = 0; ni < 4; ++ni) {
            const int col = wn + ni * 16 + fr;
            const float bv = bias[bn + col];
            #pragma unroll
            for (int mi = 0; mi < 8; ++mi) {
              const int rowl = mi * 16 + fq * 4;
              #pragma unroll
              for (int r = 0; r < 4; ++r)
                Cs[(rowl + r) * 264 + col] = f2bs(acc[mi][ni][r] + bv);
            }
          }
        }
        __syncthreads();
        #pragma unroll
        for (int it = 0; it < 4; ++it) {
          const int cid = it * 512 + tid;          // 0..2047
          const int tl = cid >> 4, rbi = cid & 15;
          const int r = hp * 128 + tl;
          const int t = tt * 4 + (r >> 6);
          const int b = r & 63;
          short* dst = xzT + ((size_t)((rb0 + rbi) * 256 + t) * 64 + b) * 64 + g * 16;
          const int4v v0 = *reinterpret_cast<const int4v*>(&Cs[tl * 264 + rbi * 16]);
          const int4v v1 = *reinterpret_cast<const int4v*>(&Cs[tl * 264 + rbi * 16 + 8]);
          asm volatile("global_store_dwordx4 %0, %1, off sc0 sc1\n\t"
                       "global_store_dwordx4 %0, %2, off offset:16 sc0 sc1"
                       :: "v"(dst), "v"(v0), "v"(v1) : "memory");
        }
      }
      asm volatile("s_waitcnt vmcnt(0)" ::: "memory");
      __syncthreads();
      if (tid == 0)
        __hip_atomic_fetch_add(&ready[tt], 1, __ATOMIC_RELAXED, __HIP_MEMORY_SCOPE_AGENT);
    }
    return;
  }

  // ================= recurrence =================
  short* Us  = (short*)smem;                   // [k>>3][c][k&7], 128 KiB
  float* zsm = (float*)(smem + 131072);        // [64 b][68], padded

  const int u0 = bid * 16;
  const int mt = wave & 3;        // batch tile (16 rows)
  const int kh = wave >> 2;       // K half
  const int gb = tid >> 3, gup = tid & 7;  // gate-math: b, unit-pair

  for (int idx = tid; idx < 1024 * 64; idx += 512) {
    const int k = idx >> 6, c = idx & 63;
    Us[((k >> 3) * 64 + c) * 8 + (k & 7)] =
        f2bs(U[(size_t)k * NG + (c >> 4) * NH + u0 + (c & 15)]);
  }
  float creg0 = 0.f, creg1 = 0.f;
  const int voff0 = kh * 131072 + kg * 2048 + mt * 512 + fr * 32;
  const int pks = bid >> 1;
  const int pkg = ((bid & 1) << 1) + (gup >> 2);
  const int pj  = (2 * gup) & 7;
  const int pidx = ((pks * 4 + pkg) * 64 + gb) * 8 + pj;
  __syncthreads();
  uint64_t rt0 = rtclock();
  int grpOK = -1;   // highest 16-step group known fully produced

  for (int t = 0; t < T_; ++t) {
    const uint32_t* __restrict__ hpv = (t & 1) ? h0buf : h1buf;  // h(t-1)
    uint32_t* __restrict__ hnx       = (t & 1) ? h1buf : h0buf;  // h(t)

    // Gate on xz availability: one dwordx4 poll per 16 steps (steady: free).
    const int grp = t >> 4;
    if (grp > grpOK) {
      if (lane == 0) {
        int spun = 0;
        for (;;) {
          int4v rv;
          asm volatile("global_load_dwordx4 %0, %1, off sc0 sc1\n\t"
                       "s_waitcnt vmcnt(0)"
                       : "=&v"(rv) : "v"(ready + grp * 4) : "memory");
          if (rv[0] == 16 && rv[1] == 16 && rv[2] == 16 && rv[3] == 16) break;
          spun = 1;
          __builtin_amdgcn_s_sleep(16);
        }
        if (spun) {  // settle: cover store->visible lag of freshest tiles
          #pragma unroll
          for (int s = 0; s < 4; ++s) __builtin_amdgcn_s_sleep(127);
        }
      }
      grpOK = grp;
    }

    int xzw[4];
    {
      const short* xb = xzT + ((((size_t)bid * 256 + t) * 64 + gb) * 64 + 2 * gup);
      asm volatile("global_load_dword %0, %4, off sc0 sc1\n\t"
                   "global_load_dword %1, %4, off offset:32 sc0 sc1\n\t"
                   "global_load_dword %2, %4, off offset:64 sc0 sc1\n\t"
                   "global_load_dword %3, %4, off offset:96 sc0 sc1"
                   : "=&v"(xzw[0]), "=&v"(xzw[1]), "=&v"(xzw[2]), "=&v"(xzw[3])
                   : "v"(xb) : "memory");
    }

    f32x4 acc[4] = {};
    if (t > 0) {
      const uint32_t tgw = (uint32_t)t << 16;  // expected tag for h(t-1)
      int4v bufA[16], bufB[16];
      while ((uint64_t)(rtclock() - rt0) < DLY_TICKS)
        __builtin_amdgcn_s_sleep(1);
      ISSUE_A; ISSUE_B;
      WAITV(16);            // xz + A landed (B in flight)
      for (;;) {
        uint32_t bad = 0; CHECKBUF(bufA);
        if (__all(bad == 0)) break;
        __builtin_amdgcn_s_sleep(4);
        ISSUE_A; WAITV(0);
      }
      MFMA_SUB(bufA, 0);
      WAITV(0);
      for (;;) {
        uint32_t bad = 0; CHECKBUF(bufB);
        if (__all(bad == 0)) break;
        __builtin_amdgcn_s_sleep(4);
        ISSUE_B; WAITV(0);
      }
      MFMA_SUB(bufB, 8);

      if (kh == 1) {
        #pragma unroll
        for (int nt = 0; nt < 4; ++nt)
          #pragma unroll
          for (int r = 0; r < 4; ++r)
            zsm[(mt * 16 + kg * 4 + r) * 68 + nt * 16 + fr] = acc[nt][r];
      }
      __syncthreads();   // S1
      if (kh == 0) {
        #pragma unroll
        for (int nt = 0; nt < 4; ++nt)
          #pragma unroll
          for (int r = 0; r < 4; ++r)
            zsm[(mt * 16 + kg * 4 + r) * 68 + nt * 16 + fr] += acc[nt][r];
      }
      __syncthreads();   // S2
    } else {
      asm volatile("s_waitcnt vmcnt(0)" ::: "memory");  // xzw landed
    }

    {  // gate math: b = gb, units u0+2*gup, u0+2*gup+1
      float z[4][2];
      #pragma unroll
      for (int g = 0; g < 4; ++g) {
        z[g][0] = bs2f((short)(xzw[g] & 0xFFFF));
        z[g][1] = bs2f((short)(((uint32_t)xzw[g]) >> 16));
        if (t > 0) {
          const float2 zz = *reinterpret_cast<const float2*>(&zsm[gb * 68 + g * 16 + 2 * gup]);
          z[g][0] += zz.x; z[g][1] += zz.y;
        }
      }
      float hh0, hh1;
      {
        const float ig = fsigm(z[0][0]), fg = fsigm(z[1][0]);
        const float gg = ftanh(z[2][0]), og = fsigm(z[3][0]);
        creg0 = fg * creg0 + ig * gg;  hh0 = og * ftanh(creg0);
      }
      {
        const float ig = fsigm(z[0][1]), fg = fsigm(z[1][1]);
        const float gg = ftanh(z[2][1]), og = fsigm(z[3][1]);
        creg1 = fg * creg1 + ig * gg;  hh1 = og * ftanh(creg1);
      }
      if (t < T_ - 1) {
        const uint32_t tgp = (uint32_t)(t + 1) << 16;
        const uint64_t hw64 =
            (uint64_t)(tgp | (uint32_t)(uint16_t)f2bs(hh0)) |
            ((uint64_t)(tgp | (uint32_t)(uint16_t)f2bs(hh1)) << 32);
        (void)__hip_atomic_exchange((uint64_t*)(hnx + pidx), hw64,
                                    __ATOMIC_RELAXED, __HIP_MEMORY_SCOPE_AGENT);
      }
      rt0 = rtclock();
      float2 o; o.x = hh0; o.y = hh1;
      *reinterpret_cast<float2*>(&out[((size_t)gb * T_ + t) * NH + u0 + 2 * gup]) = o;
    }
    __builtin_amdgcn_s_barrier();
  }
}

extern "C" void kernel_launch(void* const* d_in, const int* in_sizes, int n_in,
                              void* d_out, int out_size, void* d_ws, size_t ws_size,
                              hipStream_t stream) {
  const float* x    = (const float*)d_in[0];
  const float* W    = (const float*)d_in[1];
  const float* U    = (const float*)d_in[2];
  const float* bias = (const float*)d_in[3];
  float* out = (float*)d_out;
  char* ws = (char*)d_ws;

  // ws: xzT bf16 128 MiB | h ping/pong 2 x 256 KiB | ready 64 ints
  short*    xzT   = (short*)ws;
  uint32_t* hA    = (uint32_t*)(ws + 134217728);
  uint32_t* hB    = (uint32_t*)(ws + 134217728 + 262144);
  int*      ready = (int*)(ws + 134217728 + 524288);

  // Zero h tags + ready counters each launch (graph replays re-run this).
  hipMemsetAsync(ws + 134217728, 0, 524288 + 4096, stream);

  hipFuncSetAttribute((const void*)lstm_fused,
                      hipFuncAttributeMaxDynamicSharedMemorySize, LDS_BYTES);
  lstm_fused<<<dim3(NBLK + NWRK), dim3(512), LDS_BYTES, stream>>>(
      x, W, bias, U, xzT, hA, hB, ready, out);
}